// Round 2
// baseline (4285.787 us; speedup 1.0000x reference)
//
#include <hip/hip_runtime.h>

#define TE 16

__device__ __forceinline__ float sigm(float x){ return 1.f / (1.f + __expf(-x)); }
__device__ __forceinline__ float siluf(float x){ return x / (1.f + __expf(-x)); }
__device__ __forceinline__ void atomAddF(float* p, float v){
  __hip_atomic_fetch_add(p, v, __ATOMIC_RELAXED, __HIP_MEMORY_SCOPE_AGENT);
}

// load EC consecutive f32 from LDS
template<int EC>
__device__ __forceinline__ void ldact(const float* p, float* av){
  if constexpr (EC >= 4){
    #pragma unroll
    for (int q = 0; q < EC/4; ++q){
      float4 t = *reinterpret_cast<const float4*>(p + 4*q);
      av[4*q+0]=t.x; av[4*q+1]=t.y; av[4*q+2]=t.z; av[4*q+3]=t.w;
    }
  } else if constexpr (EC == 2){
    float2 t = *reinterpret_cast<const float2*>(p);
    av[0]=t.x; av[1]=t.y;
  } else {
    av[0]=*p;
  }
}

// load 2 consecutive f32 weights
__device__ __forceinline__ void ldw2(const float* W, int off, float* wv){
  float2 w = *reinterpret_cast<const float2*>(W + off);
  wv[0] = w.x; wv[1] = w.y;
}

// Tiled GEMV over a [K][TE] transposed LDS activation tile.
// Thread (jt,g): output cols j0..j0+NJ-1 for edges [g*EC, (g+1)*EC).
template<int K, int N, int NJ, int EG, class WL, class Post>
__device__ __forceinline__ void gemv_t(const float* pool, int actOff, WL wload, Post post){
  constexpr int JT = N / NJ;
  constexpr int EC = TE / EG;
  constexpr int ACT = JT * EG;
  static_assert(ACT <= 256 && N % NJ == 0 && TE % EG == 0, "bad cfg");
  const int tid = threadIdx.x;
  if (tid >= ACT) return;
  const int jt = tid % JT, g = tid / JT;
  const int j0 = jt * NJ, eb = g * EC;
  float acc[EC][NJ];
  #pragma unroll
  for (int e = 0; e < EC; ++e){
    #pragma unroll
    for (int t = 0; t < NJ; ++t) acc[e][t] = 0.f;
  }
  const float* ap = pool + actOff*TE + eb;
  #pragma unroll 4
  for (int k = 0; k < K; ++k){
    float av[EC]; ldact<EC>(ap + k*TE, av);
    float wv[NJ]; wload(k, j0, wv);
    #pragma unroll
    for (int t = 0; t < NJ; ++t){
      #pragma unroll
      for (int e = 0; e < EC; ++e)
        acc[e][t] = fmaf(av[e], wv[t], acc[e][t]);
    }
  }
  #pragma unroll
  for (int t = 0; t < NJ; ++t){
    #pragma unroll
    for (int e = 0; e < EC; ++e)
      post(j0 + t, eb + e, acc[e][t]);
  }
}

// ---------------- kernel 1: node pre-projections ----------------
// ms = s@Wss + bss ; ds = s@Wds ; mv/dv = einsum('nci,cd->ndi') stored [n][i*64+d]
__global__ __launch_bounds__(256) void k_node_pre(
    const float* __restrict__ node_input,
    const float* __restrict__ Wss, const float* __restrict__ bss,
    const float* __restrict__ Wsv,
    const float* __restrict__ Wds, const float* __restrict__ Wdv,
    float* __restrict__ msA, float* __restrict__ dsA,
    float* __restrict__ mvA, float* __restrict__ dvA)
{
  __shared__ __align__(16) float pl[320*TE];
  float* PL = pl;
  const int tid = threadIdx.x;
  const int n0 = blockIdx.x * TE;
  {
    int e = tid & 15, p = tid >> 4;
    const float* row = node_input + (size_t)(n0 + e)*320;
    for (int c = p; c < 128; c += 16) pl[c*TE + e] = row[c];
    for (int c = p; c < 64; c += 16){
      pl[(128 +       c)*TE + e] = row[128 + c*3 + 0];
      pl[(128 + 64  + c)*TE + e] = row[128 + c*3 + 1];
      pl[(128 + 128 + c)*TE + e] = row[128 + c*3 + 2];
    }
  }
  __syncthreads();
  gemv_t<128,128,2,4>(PL, 0,
    [=](int k,int j0,float* wv){ ldw2(Wss, k*128 + j0, wv); },
    [=](int j,int e,float v){ msA[(size_t)(n0+e)*128 + j] = bss[j] + v; });
  gemv_t<128,128,2,4>(PL, 0,
    [=](int k,int j0,float* wv){ ldw2(Wds, k*128 + j0, wv); },
    [=](int j,int e,float v){ dsA[(size_t)(n0+e)*128 + j] = v; });
  #pragma unroll
  for (int i = 0; i < 3; ++i){
    gemv_t<64,64,2,8>(PL, 128 + i*64,
      [=](int k,int j0,float* wv){ ldw2(Wsv, k*64 + j0, wv); },
      [=](int j,int e,float v){ mvA[(size_t)(n0+e)*192 + i*64 + j] = v; });
    gemv_t<64,64,2,8>(PL, 128 + i*64,
      [=](int k,int j0,float* wv){ ldw2(Wdv, k*64 + j0, wv); },
      [=](int j,int e,float v){ dvA[(size_t)(n0+e)*192 + i*64 + j] = v; });
  }
}

// ---------------- kernel 2: fused per-edge pipeline ----------------
__global__ __launch_bounds__(256) void k_edge(
    const float* __restrict__ edge_attr, const float* __restrict__ edge_emb,
    const int* __restrict__ esrc, const int* __restrict__ edst,
    const float* __restrict__ node_attr,
    const float* __restrict__ msA, const float* __restrict__ dsA,
    const float* __restrict__ mvA, const float* __restrict__ dvA,
    const float* __restrict__ rW0, const float* __restrict__ rb0,
    const float* __restrict__ rW1, const float* __restrict__ rb1,
    const float* __restrict__ rW2, const float* __restrict__ rb2,
    const float* __restrict__ l1Ws, const float* __restrict__ l1bs, const float* __restrict__ l1Wv,
    const float* __restrict__ aWs, const float* __restrict__ abs_, const float* __restrict__ adot,
    const float* __restrict__ tp2w,
    const float* __restrict__ l2Ws, const float* __restrict__ l2bs, const float* __restrict__ l2Wv,
    float* __restrict__ den, float* __restrict__ num_s, float* __restrict__ num_v)
{
  // pool row offsets (each row = TE floats). Lifetime-overlaid; see barriers.
  constexpr int O_W   = 0;    // 448 rows : per-edge tp weights (dead after gathers)
  constexpr int O_EVW = 0;    // 192 rows : w_vs*ev       (aliases w_ss/w_sv, dead)
  constexpr int O_CRW = 192;  // 192 rows : w_cr*(ev x y1) (aliases w tail; intra-thread RAW-safe)
  constexpr int O_T1  = 384;  // 64 rows
  constexpr int O_STP = 448;  // 192 rows : s_tp
  constexpr int O_T1A = 640;  // 128 rows : w_sv*es
  constexpr int O_GS  = 768;  // 192 rows : fs (0..127, silu'd) | gate (128..191, sigmoid'd)
  constexpr int O_WF  = 448;  // 160 rows (pre-STP)
  constexpr int O_H1  = 608;  // 64 rows
  constexpr int O_H2  = 672;  // 64 rows
  constexpr int O_GV  = 448;  // 192 rows : fv (aliases STP after sc)
  constexpr int O_S2  = 0;    // 192 rows (aliases EVW after gv)
  constexpr int O_U1  = 192;  // 64 rows  (aliases CRW head)
  constexpr int O_FCR = 256;  // 192 rows : cross(fv,y1) (aliases CRW tail + T1)

  __shared__ __align__(16) float pool[960*TE];
  __shared__ float y0s[TE], y1s[3*TE], zl[4*TE], lg[4*TE];
  __shared__ int srcI[TE], dstI[TE];

  float* PL = pool;
  float* ZL = zl;
  int*   DI = dstI;

  const int tid = threadIdx.x;
  const int e0 = blockIdx.x * TE;

  if (tid < TE){ srcI[tid] = esrc[e0 + tid]; dstI[tid] = edst[e0 + tid]; }
  if (tid < 64){
    int e = tid >> 2, q = tid & 3;
    float v = edge_attr[(size_t)(e0 + e)*4 + q];
    if (q == 0) y0s[e] = v; else y1s[(q-1)*TE + e] = v;
  }
  __syncthreads();

  { // wf gather: [edge_emb(32) | attr[src](64) | attr[dst](64)]
    int e = tid & 15, p = tid >> 4;
    int si = srcI[e], di = dstI[e];
    for (int c = p; c < 160; c += 16){
      float v;
      if (c < 32)       v = edge_emb[(size_t)(e0+e)*32 + c];
      else if (c < 96)  v = node_attr[(size_t)si*64 + (c-32)];
      else              v = node_attr[(size_t)di*64 + (c-96)];
      pool[(O_WF + c)*TE + e] = v;
    }
  }
  __syncthreads();

  gemv_t<160,64,2,8>(PL, O_WF,
    [=](int k,int j0,float* wv){ ldw2(rW0, k*64 + j0, wv); },
    [=](int j,int e,float v){ PL[(O_H1 + j)*TE + e] = siluf(rb0[j] + v); });
  __syncthreads();

  gemv_t<64,64,2,8>(PL, O_H1,
    [=](int k,int j0,float* wv){ ldw2(rW1, k*64 + j0, wv); },
    [=](int j,int e,float v){ PL[(O_H2 + j)*TE + e] = siluf(rb1[j] + v); });
  __syncthreads();

  gemv_t<64,448,2,1>(PL, O_H2,
    [=](int k,int j0,float* wv){ ldw2(rW2, k*448 + j0, wv); },
    [=](int j,int e,float v){ PL[(O_W + j)*TE + e] = rb2[j] + v; });
  __syncthreads();

  { // es gather: o0a -> s_tp[0:128), t1act = w_sv*es
    int e = tid & 15, p = tid >> 4;
    int si = srcI[e], di = dstI[e];
    float yy0 = y0s[e];
    for (int c = p; c < 128; c += 16){
      float es = msA[(size_t)si*128 + c] + dsA[(size_t)di*128 + c];
      pool[(O_STP + c)*TE + e] = pool[(O_W + c)*TE + e] * es * yy0;
      pool[(O_T1A + c)*TE + e] = pool[(O_W + 128 + c)*TE + e] * es;
    }
  }
  __syncthreads();

  { // ev gather: o0b -> s_tp[128:192), evw = w_vs*ev, crw = w_cr*(ev x y1)
    // NOTE: crw rows [256,384) overwrite w_vs/w_dt, but only at the same (c,e)
    // element the same thread already read this iteration (read precedes write).
    int e = tid & 15, p = tid >> 4;
    int si = srcI[e], di = dstI[e];
    float y10 = y1s[e], y11 = y1s[TE + e], y12 = y1s[2*TE + e];
    for (int c = p; c < 64; c += 16){
      float ev0 = mvA[(size_t)si*192 +       c] + dvA[(size_t)di*192 +       c];
      float ev1 = mvA[(size_t)si*192 + 64  + c] + dvA[(size_t)di*192 + 64  + c];
      float ev2 = mvA[(size_t)si*192 + 128 + c] + dvA[(size_t)di*192 + 128 + c];
      float wvs = pool[(O_W + 256 + c)*TE + e];
      float wdt = pool[(O_W + 320 + c)*TE + e];
      float wcr = pool[(O_W + 384 + c)*TE + e];
      pool[(O_STP + 128 + c)*TE + e] = wdt * (ev0*y10 + ev1*y11 + ev2*y12);
      pool[(O_EVW +       c)*TE + e] = wvs * ev0;
      pool[(O_EVW + 64  + c)*TE + e] = wvs * ev1;
      pool[(O_EVW + 128 + c)*TE + e] = wvs * ev2;
      pool[(O_CRW +       c)*TE + e] = wcr * (ev1*y12 - ev2*y11);
      pool[(O_CRW + 64  + c)*TE + e] = wcr * (ev2*y10 - ev0*y12);
      pool[(O_CRW + 128 + c)*TE + e] = wcr * (ev0*y11 - ev1*y10);
    }
  }
  __syncthreads();

  // t1 = (w_sv*es) @ lin1_Wv[0:128)      (no cross-thread hazards with gs/sc)
  gemv_t<128,64,2,8>(PL, O_T1A,
    [=](int k,int j0,float* wv){ ldw2(l1Wv, k*64 + j0, wv); },
    [=](int j,int e,float v){ PL[(O_T1 + j)*TE + e] = v; });

  // gs = s_tp @ lin1_Ws + b ; store silu (j<128) / sigmoid gate (j>=128)
  gemv_t<192,192,2,2>(PL, O_STP,
    [=](int k,int j0,float* wv){ ldw2(l1Ws, k*192 + j0, wv); },
    [=](int j,int e,float v){
      float t = l1bs[j] + v;
      PL[(O_GS + j)*TE + e] = (j < 128) ? siluf(t) : sigm(t);
    });

  // sc = s_tp @ att_Ws + b -> smooth_leaky -> logits (reduce 32-lane groups)
  if (tid < 128){
    int j = tid;
    float acc[TE];
    #pragma unroll
    for (int e = 0; e < TE; ++e) acc[e] = 0.f;
    #pragma unroll 2
    for (int k = 0; k < 192; ++k){
      float av[TE]; ldact<TE>(&pool[(O_STP + k)*TE], av);
      float w = aWs[k*128 + j];
      #pragma unroll
      for (int e = 0; e < TE; ++e) acc[e] = fmaf(av[e], w, acc[e]);
    }
    float bb = abs_[j];
    float dt = adot[j];
    int h = j >> 5;
    #pragma unroll
    for (int e = 0; e < TE; ++e){
      float t = acc[e] + bb;
      float a = t * (0.2f + 0.8f * sigm(t));   // smooth_leaky(alpha=0.2)
      float c = a * dt;
      c += __shfl_xor(c, 1, 32);
      c += __shfl_xor(c, 2, 32);
      c += __shfl_xor(c, 4, 32);
      c += __shfl_xor(c, 8, 32);
      c += __shfl_xor(c, 16, 32);
      if ((j & 31) == 0) lg[h*TE + e] = c;
    }
  }
  __syncthreads();

  if (tid < 64){ // z = exp(logit) (max-free; logits O(few) << 88), den += z
    int e = tid & 15, h = tid >> 4;
    float z = __expf(lg[h*TE + e]);
    zl[h*TE + e] = z;
    atomAddF(&den[(size_t)dstI[e]*4 + h], z);
  }
  __syncthreads();

  // gv = y1*t1 + y0*(evw@Wv2) + crw@Wv3 ; fv = gv * gate  -> O_GV
  if (tid < 192){
    int g = tid / 96, r = tid % 96;
    int i = r / 32, d0 = (r % 32) * 2;
    int eb = g * 8;
    float accP[8][2], accY[8][2];
    #pragma unroll
    for (int e = 0; e < 8; ++e){
      float y1v = y1s[i*TE + eb + e];
      accP[e][0] = y1v * pool[(O_T1 + d0    )*TE + eb + e];
      accP[e][1] = y1v * pool[(O_T1 + d0 + 1)*TE + eb + e];
      accY[e][0] = 0.f; accY[e][1] = 0.f;
    }
    #pragma unroll 2
    for (int k = 0; k < 64; ++k){
      float av[8], cv[8];
      ldact<8>(&pool[(O_EVW + i*64 + k)*TE + eb], av);
      ldact<8>(&pool[(O_CRW + i*64 + k)*TE + eb], cv);
      float w2[2], w3[2];
      ldw2(l1Wv, (128 + k)*64 + d0, w2);
      ldw2(l1Wv, (192 + k)*64 + d0, w3);
      #pragma unroll
      for (int e = 0; e < 8; ++e){
        accY[e][0] = fmaf(av[e], w2[0], accY[e][0]);
        accY[e][1] = fmaf(av[e], w2[1], accY[e][1]);
        accP[e][0] = fmaf(cv[e], w3[0], accP[e][0]);
        accP[e][1] = fmaf(cv[e], w3[1], accP[e][1]);
      }
    }
    #pragma unroll
    for (int t = 0; t < 2; ++t){
      int d = d0 + t;
      #pragma unroll
      for (int e = 0; e < 8; ++e){
        int ee = eb + e;
        float val = accP[e][t] + y0s[ee]*accY[e][t];
        float gate = pool[(O_GS + 128 + d)*TE + ee];
        pool[(O_GV + i*64 + d)*TE + ee] = val * gate;
      }
    }
  }
  __syncthreads();

  { // s2 (dtp2 scalar part) + fcr = cross(fv, y1)
    int e = tid & 15, p = tid >> 4;
    float yy0 = y0s[e];
    float y10 = y1s[e], y11 = y1s[TE + e], y12 = y1s[2*TE + e];
    for (int c = p; c < 128; c += 16){
      pool[(O_S2 + c)*TE + e] = tp2w[c] * pool[(O_GS + c)*TE + e] * yy0;
    }
    for (int c = p; c < 64; c += 16){
      float f0 = pool[(O_GV +       c)*TE + e];
      float f1 = pool[(O_GV + 64  + c)*TE + e];
      float f2 = pool[(O_GV + 128 + c)*TE + e];
      pool[(O_S2 + 128 + c)*TE + e] = tp2w[320 + c] * (f0*y10 + f1*y11 + f2*y12);
      pool[(O_FCR +       c)*TE + e] = f1*y12 - f2*y11;
      pool[(O_FCR + 64  + c)*TE + e] = f2*y10 - f0*y12;
      pool[(O_FCR + 128 + c)*TE + e] = f0*y11 - f1*y10;
    }
  }
  // u1 = (t_sv * fs) @ lin2_Wv[0:128)   (scale folded into W load)
  gemv_t<128,64,2,8>(PL, O_GS,
    [=](int k,int j0,float* wv){
      float s = tp2w[128 + k];
      ldw2(l2Wv, k*64 + j0, wv);
      wv[0] *= s; wv[1] *= s;
    },
    [=](int j,int e,float v){ PL[(O_U1 + j)*TE + e] = v; });
  __syncthreads();

  // val_s = s2 @ lin2_Ws + b ; scatter num_s += val_s * z
  gemv_t<192,128,2,4>(PL, O_S2,
    [=](int k,int j0,float* wv){ ldw2(l2Ws, k*128 + j0, wv); },
    [=](int j,int e,float v){
      float vv = (l2bs[j] + v) * ZL[(j >> 5)*TE + e];
      atomAddF(&num_s[(size_t)DI[e]*128 + j], vv);
    });

  // val_v = y1*u1 + y0*((t_vs*fv)@Wv2') + (t_cr*fcr)@Wv3' ; scatter num_v += val_v*z
  if (tid < 192){
    int g = tid / 96, r = tid % 96;
    int i = r / 32, d0 = (r % 32) * 2;
    int eb = g * 8;
    float accP[8][2], accY[8][2];
    #pragma unroll
    for (int e = 0; e < 8; ++e){
      float y1v = y1s[i*TE + eb + e];
      accP[e][0] = y1v * pool[(O_U1 + d0    )*TE + eb + e];
      accP[e][1] = y1v * pool[(O_U1 + d0 + 1)*TE + eb + e];
      accY[e][0] = 0.f; accY[e][1] = 0.f;
    }
    #pragma unroll 2
    for (int k = 0; k < 64; ++k){
      float av[8], cv[8];
      ldact<8>(&pool[(O_GV  + i*64 + k)*TE + eb], av);
      ldact<8>(&pool[(O_FCR + i*64 + k)*TE + eb], cv);
      float w2[2], w3[2];
      float s2c = tp2w[256 + k];
      float s3c = tp2w[384 + k];
      ldw2(l2Wv, (128 + k)*64 + d0, w2);
      ldw2(l2Wv, (192 + k)*64 + d0, w3);
      w2[0]*=s2c; w2[1]*=s2c; w3[0]*=s3c; w3[1]*=s3c;
      #pragma unroll
      for (int e = 0; e < 8; ++e){
        accY[e][0] = fmaf(av[e], w2[0], accY[e][0]);
        accY[e][1] = fmaf(av[e], w2[1], accY[e][1]);
        accP[e][0] = fmaf(cv[e], w3[0], accP[e][0]);
        accP[e][1] = fmaf(cv[e], w3[1], accP[e][1]);
      }
    }
    #pragma unroll
    for (int t = 0; t < 2; ++t){
      int d = d0 + t;
      int h = d >> 4;
      #pragma unroll
      for (int e = 0; e < 8; ++e){
        int ee = eb + e;
        float val = accP[e][t] + y0s[ee]*accY[e][t];
        atomAddF(&num_v[(size_t)dstI[ee]*192 + i*64 + d], val * zl[h*TE + ee]);
      }
    }
  }
}

// ---------------- kernel 3: normalize + output projections ----------------
__global__ __launch_bounds__(256) void k_node_out(
    const float* __restrict__ den, const float* __restrict__ num_s, const float* __restrict__ num_v,
    const float* __restrict__ Wos, const float* __restrict__ bos, const float* __restrict__ Wov,
    float* __restrict__ out)
{
  __shared__ __align__(16) float pl[320*TE];
  __shared__ float dl[4*TE];
  float* PL = pl;
  const int tid = threadIdx.x;
  const int n0 = blockIdx.x * TE;
  if (tid < 64){
    int e = tid & 15, h = tid >> 4;
    dl[h*TE + e] = den[(size_t)(n0 + e)*4 + h] + 1e-12f;
  }
  __syncthreads();
  {
    int e = tid & 15, p = tid >> 4;
    for (int c = p; c < 128; c += 16)
      pl[c*TE + e] = num_s[(size_t)(n0+e)*128 + c] / dl[(c >> 5)*TE + e];
    for (int c = p; c < 64; c += 16){
      float dd = dl[(c >> 4)*TE + e];
      pl[(128 +       c)*TE + e] = num_v[(size_t)(n0+e)*192 +       c] / dd;
      pl[(128 + 64  + c)*TE + e] = num_v[(size_t)(n0+e)*192 + 64  + c] / dd;
      pl[(128 + 128 + c)*TE + e] = num_v[(size_t)(n0+e)*192 + 128 + c] / dd;
    }
  }
  __syncthreads();
  gemv_t<128,128,2,4>(PL, 0,
    [=](int k,int j0,float* wv){ ldw2(Wos, k*128 + j0, wv); },
    [=](int j,int e,float v){ out[(size_t)(n0+e)*320 + j] = bos[j] + v; });
  #pragma unroll
  for (int i = 0; i < 3; ++i){
    gemv_t<64,64,2,8>(PL, 128 + i*64,
      [=](int k,int j0,float* wv){ ldw2(Wov, k*64 + j0, wv); },
      [=](int j,int e,float v){ out[(size_t)(n0+e)*320 + 128 + j*3 + i] = v; });
  }
}

extern "C" void kernel_launch(void* const* d_in, const int* in_sizes, int n_in,
                              void* d_out, int out_size, void* d_ws, size_t ws_size,
                              hipStream_t stream)
{
  const float* node_input = (const float*)d_in[0];
  const float* node_attr  = (const float*)d_in[1];
  const float* edge_attr  = (const float*)d_in[2];
  const float* edge_emb   = (const float*)d_in[3];
  const int* edge_src   = (const int*)d_in[4];
  const int* edge_dst   = (const int*)d_in[5];
  const float* W_src_s = (const float*)d_in[6];
  const float* b_src_s = (const float*)d_in[7];
  const float* W_src_v = (const float*)d_in[8];
  const float* W_dst_s = (const float*)d_in[9];
  const float* W_dst_v = (const float*)d_in[10];
  const float* rad_W0  = (const float*)d_in[11];
  const float* rad_b0  = (const float*)d_in[12];
  const float* rad_W1  = (const float*)d_in[13];
  const float* rad_b1  = (const float*)d_in[14];
  const float* rad_W2  = (const float*)d_in[15];
  const float* rad_b2  = (const float*)d_in[16];
  const float* lin1_Ws = (const float*)d_in[17];
  const float* lin1_bs = (const float*)d_in[18];
  const float* lin1_Wv = (const float*)d_in[19];
  const float* att_Ws  = (const float*)d_in[20];
  const float* att_bs  = (const float*)d_in[21];
  const float* tp2_w   = (const float*)d_in[22];
  const float* lin2_Ws = (const float*)d_in[23];
  const float* lin2_bs = (const float*)d_in[24];
  const float* lin2_Wv = (const float*)d_in[25];
  const float* att_dot = (const float*)d_in[26];
  const float* out_Ws  = (const float*)d_in[27];
  const float* out_bs  = (const float*)d_in[28];
  const float* out_Wv  = (const float*)d_in[29];

  const int nN = in_sizes[0] / 320;   // 10000
  const int nE = in_sizes[4];         // 320000

  float* ws    = (float*)d_ws;
  float* den   = ws;
  float* num_s = den   + (size_t)nN * 4;
  float* num_v = num_s + (size_t)nN * 128;
  float* msA   = num_v + (size_t)nN * 192;
  float* dsA   = msA   + (size_t)nN * 128;
  float* mvA   = dsA   + (size_t)nN * 128;
  float* dvA   = mvA   + (size_t)nN * 192;

  size_t need = ((size_t)nN * (4 + 128 + 192 + 128 + 128 + 192 + 192)) * sizeof(float);
  if (ws_size < need) return;  // fail loudly (output stays poisoned)

  hipMemsetAsync(den, 0, (size_t)nN * (4 + 128 + 192) * sizeof(float), stream);

  k_node_pre<<<nN/TE, 256, 0, stream>>>(node_input, W_src_s, b_src_s, W_src_v,
                                        W_dst_s, W_dst_v, msA, dsA, mvA, dvA);
  k_edge<<<nE/TE, 256, 0, stream>>>(edge_attr, edge_emb, edge_src, edge_dst, node_attr,
                                    msA, dsA, mvA, dvA,
                                    rad_W0, rad_b0, rad_W1, rad_b1, rad_W2, rad_b2,
                                    lin1_Ws, lin1_bs, lin1_Wv,
                                    att_Ws, att_bs, att_dot,
                                    tp2_w, lin2_Ws, lin2_bs, lin2_Wv,
                                    den, num_s, num_v);
  k_node_out<<<nN/TE, 256, 0, stream>>>(den, num_s, num_v, out_Ws, out_bs, out_Wv,
                                        (float*)d_out);
}